// Round 8
// baseline (37.514 us; speedup 1.0000x reference)
//
#include <hip/hip_runtime.h>
#include <cmath>

// SpikesToTimesDecoder: input [T, B, N] fp32 0/1 raster -> output [3, B, N]
// fp32 times (t * 0.001) of the first 3 spikes per channel, inf-padded.
//
// Final model (R1-R7 measured): this scattered column-scan read pattern is
// service-capped at ~3.3 TB/s on this chip REGARDLESS of granule size
// (256 B vs 1 KB), MLP depth, or pipeline style (R1/R2/R7 all land at 3.3;
// R2's marginal Dbytes/Dtime = 3.3). Therefore time = bytes/3.3, and the
// only lever is bytes issued before each wave's exit decision.
//
// Design (byte-minimal R1 variant): one thread per channel, lane i reads
// channel base+i -> 256 B coalesced per wave-step. Issue-drain chunks of
// CHUNK=8 rows (halves R1's exit-rounding waste vs CHUNK=16, ~4% fewer
// bytes; 8 outstanding loads/thread x 2048 waves ~ 4.2 MB in flight still
// covers the ~4 MB bandwidth-delay product). Per-wave early exit when all
// 64 lanes have 3 spikes (mean exit t ~ 175 of 512 at 5% spike rate).

constexpr int K_SPIKES = 3;
constexpr int CHUNK = 8;

__global__ __launch_bounds__(256) void spikes_to_times_kernel(
    const float* __restrict__ in, float* __restrict__ out,
    int BN, int T, float dt) {
  const int c = blockIdx.x * blockDim.x + threadIdx.x;
  if (c >= BN) return;

  float t0 = INFINITY, t1 = INFINITY, t2 = INFINITY;
  int cnt = 0;
  const float* p = in + c;

  for (int t = 0; t < T; t += CHUNK) {
    float v[CHUNK];
#pragma unroll
    for (int j = 0; j < CHUNK; ++j) {
      const int row = (t + j < T) ? (t + j) : (T - 1);  // clamp (T%CHUNK!=0 safety)
      v[j] = p[(size_t)row * (size_t)BN];
    }
#pragma unroll
    for (int j = 0; j < CHUNK; ++j) {
      const bool s = (v[j] > 0.0f) && (t + j < T);
      const float tt = (float)(t + j);
      if (s && cnt == 0) t0 = tt;
      if (s && cnt == 1) t1 = tt;
      if (s && cnt == 2) t2 = tt;
      cnt += s ? 1 : 0;
    }
    if (__all(cnt >= K_SPIKES)) break;  // wave-uniform early exit
  }

  out[c] = t0 * dt;
  out[BN + c] = t1 * dt;
  out[2 * (size_t)BN + c] = t2 * dt;
}

extern "C" void kernel_launch(void* const* d_in, const int* in_sizes, int n_in,
                              void* d_out, int out_size, void* d_ws, size_t ws_size,
                              hipStream_t stream) {
  const float* in = (const float*)d_in[0];
  float* out = (float*)d_out;

  const int BN = out_size / K_SPIKES;  // B * N channels
  const int T = in_sizes[0] / BN;      // timesteps

  const int block = 256;
  const int grid = (BN + block - 1) / block;
  hipLaunchKernelGGL(spikes_to_times_kernel, dim3(grid), dim3(block), 0, stream,
                     in, out, BN, T, 0.001f);
}

// Round 9
// 26.893 us; speedup vs baseline: 1.3949x; 1.3949x over previous
//
#include <hip/hip_runtime.h>
#include <cmath>

// SpikesToTimesDecoder: input [T, B, N] fp32 0/1 raster -> output [3, B, N]
// fp32 times (t * 0.001) of the first 3 spikes per channel, inf-padded.
//
// FINAL (R1 config — best measured, 27.1 us). Model from R1-R8:
//   - MI355X read-service ceiling ~3.3-3.5 TB/s for this kernel class,
//     independent of granule size (256 B vs 1 KB), pipeline style, and
//     MLP beyond the knee (~16 outstanding loads/wave; 8 starves to 2.4,
//     64 gains nothing). Read/write service is asymmetric (fills post
//     writes at 7 TB/s; copy = 3.15R+3.15W).
//   - Bytes floor: per-wave exit = max-of-64 third-spike ~ 170 rows;
//     CHUNK=16 rounding -> ~92 MB total. Finer chunks save 4% bytes but
//     lose 30% throughput (R8); coarser wastes bytes (R2-overshoot).
// 92 MB / 3.4 TB/s ~ 27 us = measured. This is the roofline.
//
// One thread per channel; lane i reads channel base+i -> 256 B coalesced
// per wave-step. CHUNK=16 issue-drain (16 outstanding dword loads/thread),
// branchless first-3 conditional chain, per-wave early exit via __all.

constexpr int K_SPIKES = 3;
constexpr int CHUNK = 16;

__global__ __launch_bounds__(256) void spikes_to_times_kernel(
    const float* __restrict__ in, float* __restrict__ out,
    int BN, int T, float dt) {
  const int c = blockIdx.x * blockDim.x + threadIdx.x;
  if (c >= BN) return;

  float t0 = INFINITY, t1 = INFINITY, t2 = INFINITY;
  int cnt = 0;
  const float* p = in + c;

  for (int t = 0; t < T; t += CHUNK) {
    float v[CHUNK];
#pragma unroll
    for (int j = 0; j < CHUNK; ++j) {
      v[j] = p[(size_t)(t + j) * (size_t)BN];
    }
#pragma unroll
    for (int j = 0; j < CHUNK; ++j) {
      const bool s = v[j] > 0.0f;
      const float tt = (float)(t + j);
      if (s && cnt == 0) t0 = tt;
      if (s && cnt == 1) t1 = tt;
      if (s && cnt == 2) t2 = tt;
      cnt += s ? 1 : 0;
    }
    // Whole wave done? (all 64 lanes found K_SPIKES spikes)
    if (__all(cnt >= K_SPIKES)) break;
  }

  out[c]          = t0 * dt;
  out[BN + c]     = t1 * dt;
  out[2 * BN + c] = t2 * dt;
}

extern "C" void kernel_launch(void* const* d_in, const int* in_sizes, int n_in,
                              void* d_out, int out_size, void* d_ws, size_t ws_size,
                              hipStream_t stream) {
  const float* in = (const float*)d_in[0];
  float* out = (float*)d_out;

  const int BN = out_size / K_SPIKES;  // B * N channels
  const int T = in_sizes[0] / BN;      // timesteps

  const int block = 256;
  const int grid = (BN + block - 1) / block;
  hipLaunchKernelGGL(spikes_to_times_kernel, dim3(grid), dim3(block), 0, stream,
                     in, out, BN, T, 0.001f);
}